// Round 13
// baseline (186.023 us; speedup 1.0000x reference)
//
#include <hip/hip_runtime.h>
#include <math.h>

typedef float f2 __attribute__((ext_vector_type(2)));
typedef float f2u __attribute__((ext_vector_type(2), aligned(4)));

#define BN 8
#define CIN 3
#define HH 512
#define WW 512
#define KK 9
#define PATCH 27
#define TAPBLK 96  // 56 (wy,wx) pair floats | 28 wm | 12 contraction = 96 = 6x dwordx16

// ws layout, tap k block of 96 floats (identical to r5/r9/r11 — proven):
//  r in [0,56):  pair q=r>>1, half=r&1 -> w_off[(2k+half)*27+q], q>=27 -> 0
//  r in [56,84): i=r-56 -> w_off[(18+k)*27+i], i>=27 -> 0
//  r in [84,96): j=r-84, c=j>>2, o=j&3 -> o<3 ? w_def[o*27 + c*9 + k] : 0
__global__ void reorder_weights(const float* __restrict__ w_off,
                                const float* __restrict__ w_def,
                                float* __restrict__ ws)
{
    for (int idx = threadIdx.x; idx < KK * TAPBLK; idx += blockDim.x) {
        const int k = idx / TAPBLK;
        const int r = idx % TAPBLK;
        float v = 0.0f;
        if (r < 56) {
            const int q = r >> 1, half = r & 1;
            if (q < PATCH) v = w_off[(2 * k + half) * PATCH + q];
        } else if (r < 84) {
            const int i = r - 56;
            if (i < PATCH) v = w_off[(18 + k) * PATCH + i];
        } else {
            const int j = r - 84;
            const int c = j >> 2, o = j & 3;
            if (o < 3) v = w_def[o * PATCH + c * KK + k];
        }
        ws[idx] = v;
    }
}

// 1024-thread workgroups (16 waves/WG): tests the WG-slot-residency theory.
// Per-thread code identical to the proven r9/r11 body (VGPR ~48, no LDS).
__global__ __launch_bounds__(1024) void deform_fused_kernel(
    const float* __restrict__ x,
    const float* __restrict__ wsw,    // reordered weights, 864 floats (uniform -> SMEM)
    const float* __restrict__ b_off,
    const float* __restrict__ b_def,
    float* __restrict__ out)
{
    // ---- XCD-aware swizzle (r11-proven mechanism: FETCH 55 -> 12.4 MB).
    //      2048 blocks, 2048 % 8 == 0 -> bijective. Each XCD gets one
    //      contiguous 256-block chunk = one full batch. Each block = 2 rows.
    const int bid = blockIdx.x;
    const int W = (bid & 7) * 256 + (bid >> 3);
    const int b  = W >> 8;                  // batch 0..7 (one per XCD)
    const int r2 = W & 255;                 // row-pair 0..255

    const int t = threadIdx.x;              // 0..1023
    const int h = r2 * 2 + (t >> 9);        // row
    const int w = t & 511;                  // col

    const size_t plane = (size_t)HH * WW;
    const float* xb = x + (size_t)b * CIN * plane;

    // ---- 3x3x3 zero-padded patch, flat index = c*9 + t; pad elem 27 = 0 ----
    float patch[28];
    patch[27] = 0.0f;
    #pragma unroll
    for (int c = 0; c < CIN; ++c) {
        const float* xp = xb + c * plane;
        #pragma unroll
        for (int tt = 0; tt < KK; ++tt) {
            const int yy = h + tt / 3 - 1;
            const int xx = w + tt % 3 - 1;
            const bool in = (yy >= 0) & (yy < HH) & (xx >= 0) & (xx < WW);
            patch[c * KK + tt] = in ? xp[yy * WW + xx] : 0.0f;
        }
    }

    const float hf = (float)h;
    const float wf = (float)w;

    float acc0 = b_def[0];
    float acc1 = b_def[1];
    float acc2 = b_def[2];

    // ---- prologue: conv for tap 0, all-scalar fmaf (weights from SGPR) ----
    float oy, ox, om;
    {
        const float* blk = wsw;   // tap 0
        float a0 = b_off[0], a1 = b_off[1], s = b_off[18];
        #pragma unroll
        for (int q = 0; q < 28; ++q) {
            a0 = fmaf(blk[2 * q],     patch[q], a0);
            a1 = fmaf(blk[2 * q + 1], patch[q], a1);
        }
        #pragma unroll
        for (int i = 0; i < 28; ++i) {
            s = fmaf(blk[56 + i], patch[i], s);
        }
        oy = a0; ox = a1; om = s;
    }

    // ---- software-pipelined tap loop (r9 schedule, scalar arithmetic) ----
    // iteration k: (A) issue gathers for tap k-1  (B) conv tap k  (C) consume tap k-1
    #pragma unroll 1
    for (int k = 1; k <= KK; ++k) {
        const int kp = k - 1;
        const float* blkp = wsw + kp * TAPBLK;

        // -- phase A: contraction weights (uniform scalars) + sampling for tap kp --
        const float cw00 = blkp[84], cw01 = blkp[85], cw02 = blkp[86];
        const float cw10 = blkp[88], cw11 = blkp[89], cw12 = blkp[90];
        const float cw20 = blkp[92], cw21 = blkp[93], cw22 = blkp[94];

        const float m = 1.0f / (1.0f + __expf(-om));

        const float py = hf + (float)(kp / 3 - 1) + oy;
        const float px = wf + (float)(kp % 3 - 1) + ox;
        const float y0f = floorf(py);
        const float x0f = floorf(px);
        const float dy = py - y0f;
        const float dx = px - x0f;
        const int y0 = (int)y0f;
        const int x0 = (int)x0f;

        const float omdy = 1.0f - dy;
        const float omdx = 1.0f - dx;
        const float w00 = omdx * omdy;
        const float w01 = dx * omdy;
        const float w10 = omdx * dy;
        const float w11 = dx * dy;

        const int interior = (y0 >= 0) & (y0 + 1 < HH) & (x0 >= 0) & (x0 + 1 < WW);

        f2 vT0, vB0, vT1, vB1, vT2, vB2;   // gathered 2x2 corners per channel
        if (__all(interior)) {
            const int idx = y0 * WW + x0;
            const float* xp0 = xb + idx;
            const float* xp1 = xp0 + plane;
            const float* xp2 = xp1 + plane;
            vT0 = *(const f2u*)(xp0);  vB0 = *(const f2u*)(xp0 + WW);
            vT1 = *(const f2u*)(xp1);  vB1 = *(const f2u*)(xp1 + WW);
            vT2 = *(const f2u*)(xp2);  vB2 = *(const f2u*)(xp2 + WW);
        } else {
            const bool vy0 = (y0 >= 0)     & (y0 < HH);
            const bool vy1 = (y0 + 1 >= 0) & (y0 + 1 < HH);
            const bool vx0 = (x0 >= 0)     & (x0 < WW);
            const bool vx1 = (x0 + 1 >= 0) & (x0 + 1 < WW);

            const int yc0 = min(max(y0, 0), HH - 1);
            const int yc1 = min(max(y0 + 1, 0), HH - 1);
            const int xc0 = min(max(x0, 0), WW - 1);
            const int xc1 = min(max(x0 + 1, 0), WW - 1);

            const float* xp0 = xb;
            const float* xp1 = xp0 + plane;
            const float* xp2 = xp1 + plane;

            vT0.x = (vy0 & vx0) ? xp0[yc0 * WW + xc0] : 0.0f;
            vT0.y = (vy0 & vx1) ? xp0[yc0 * WW + xc1] : 0.0f;
            vB0.x = (vy1 & vx0) ? xp0[yc1 * WW + xc0] : 0.0f;
            vB0.y = (vy1 & vx1) ? xp0[yc1 * WW + xc1] : 0.0f;
            vT1.x = (vy0 & vx0) ? xp1[yc0 * WW + xc0] : 0.0f;
            vT1.y = (vy0 & vx1) ? xp1[yc0 * WW + xc1] : 0.0f;
            vB1.x = (vy1 & vx0) ? xp1[yc1 * WW + xc0] : 0.0f;
            vB1.y = (vy1 & vx1) ? xp1[yc1 * WW + xc1] : 0.0f;
            vT2.x = (vy0 & vx0) ? xp2[yc0 * WW + xc0] : 0.0f;
            vT2.y = (vy0 & vx1) ? xp2[yc0 * WW + xc1] : 0.0f;
            vB2.x = (vy1 & vx0) ? xp2[yc1 * WW + xc0] : 0.0f;
            vB2.y = (vy1 & vx1) ? xp2[yc1 * WW + xc1] : 0.0f;
        }

        // -- phase B: conv for tap k, all-scalar (independent of in-flight gathers) --
        if (k < KK) {
            const float* blk = wsw + k * TAPBLK;
            float a0 = b_off[2 * k], a1 = b_off[2 * k + 1], s = b_off[18 + k];
            #pragma unroll
            for (int q = 0; q < 28; ++q) {
                a0 = fmaf(blk[2 * q],     patch[q], a0);
                a1 = fmaf(blk[2 * q + 1], patch[q], a1);
            }
            #pragma unroll
            for (int i = 0; i < 28; ++i) {
                s = fmaf(blk[56 + i], patch[i], s);
            }
            oy = a0; ox = a1; om = s;
        }

        // -- phase C: consume tap kp's gathers, all-scalar --
        {
            float v0 = vT0.x * w00;
            v0 = fmaf(vT0.y, w01, v0);
            v0 = fmaf(vB0.x, w10, v0);
            v0 = fmaf(vB0.y, w11, v0);
            const float val0 = v0 * m;

            float v1 = vT1.x * w00;
            v1 = fmaf(vT1.y, w01, v1);
            v1 = fmaf(vB1.x, w10, v1);
            v1 = fmaf(vB1.y, w11, v1);
            const float val1 = v1 * m;

            float v2 = vT2.x * w00;
            v2 = fmaf(vT2.y, w01, v2);
            v2 = fmaf(vB2.x, w10, v2);
            v2 = fmaf(vB2.y, w11, v2);
            const float val2 = v2 * m;

            acc0 = fmaf(cw00, val0, acc0);
            acc1 = fmaf(cw01, val0, acc1);
            acc2 = fmaf(cw02, val0, acc2);
            acc0 = fmaf(cw10, val1, acc0);
            acc1 = fmaf(cw11, val1, acc1);
            acc2 = fmaf(cw12, val1, acc2);
            acc0 = fmaf(cw20, val2, acc0);
            acc1 = fmaf(cw21, val2, acc1);
            acc2 = fmaf(cw22, val2, acc2);
        }
    }

    const size_t base = (size_t)b * (CIN * plane) + (size_t)h * WW + w;
    out[base]             = acc0;
    out[base + plane]     = acc1;
    out[base + 2 * plane] = acc2;
}

extern "C" void kernel_launch(void* const* d_in, const int* in_sizes, int n_in,
                              void* d_out, int out_size, void* d_ws, size_t ws_size,
                              hipStream_t stream) {
    const float* x     = (const float*)d_in[0];
    const float* w_off = (const float*)d_in[1];
    const float* b_off = (const float*)d_in[2];
    const float* w_def = (const float*)d_in[3];
    const float* b_def = (const float*)d_in[4];
    float* out = (float*)d_out;
    float* wsw = (float*)d_ws;   // 864 floats of reordered weights

    reorder_weights<<<1, 256, 0, stream>>>(w_off, w_def, wsw);

    dim3 block(1024, 1, 1);
    dim3 grid(2048, 1, 1);   // flat; in-kernel XCD-aware swizzle decodes (b, row-pair)
    deform_fused_kernel<<<grid, block, 0, stream>>>(x, wsw, b_off, b_def, out);
}

// Round 14
// 180.201 us; speedup vs baseline: 1.0323x; 1.0323x over previous
//
#include <hip/hip_runtime.h>
#include <math.h>

typedef float f2 __attribute__((ext_vector_type(2)));
typedef float f2u __attribute__((ext_vector_type(2), aligned(4)));

#define BN 8
#define CIN 3
#define HH 512
#define WW 512
#define KK 9
#define PATCH 27
#define TAPBLK 96  // 56 (wy,wx) pair floats | 28 wm | 12 contraction = 96 = 6x dwordx16

// ws layout, tap k block of 96 floats (identical to r5/r9/r11 — proven):
//  r in [0,56):  pair q=r>>1, half=r&1 -> w_off[(2k+half)*27+q], q>=27 -> 0
//  r in [56,84): i=r-56 -> w_off[(18+k)*27+i], i>=27 -> 0
//  r in [84,96): j=r-84, c=j>>2, o=j&3 -> o<3 ? w_def[o*27 + c*9 + k] : 0
__global__ void reorder_weights(const float* __restrict__ w_off,
                                const float* __restrict__ w_def,
                                float* __restrict__ ws)
{
    for (int idx = threadIdx.x; idx < KK * TAPBLK; idx += blockDim.x) {
        const int k = idx / TAPBLK;
        const int r = idx % TAPBLK;
        float v = 0.0f;
        if (r < 56) {
            const int q = r >> 1, half = r & 1;
            if (q < PATCH) v = w_off[(2 * k + half) * PATCH + q];
        } else if (r < 84) {
            const int i = r - 56;
            if (i < PATCH) v = w_off[(18 + k) * PATCH + i];
        } else {
            const int j = r - 84;
            const int c = j >> 2, o = j & 3;
            if (o < 3) v = w_def[o * PATCH + c * KK + k];
        }
        ws[idx] = v;
    }
}

__global__ __launch_bounds__(256) void deform_fused_kernel(
    const float* __restrict__ x,
    const float* __restrict__ wsw,    // reordered weights, 864 floats (uniform -> SMEM)
    const float* __restrict__ b_off,
    const float* __restrict__ b_def,
    float* __restrict__ out)
{
    // ---- XCD-aware swizzle (r11-proven: FETCH 55 -> 12.4 MB) ----
    const int bid = blockIdx.x;
    const int W = (bid & 7) * 1024 + (bid >> 3);   // bijective, 8192 % 8 == 0
    const int b  = W >> 10;            // batch 0..7  (one per XCD)
    const int C  = W & 1023;
    const int h  = C >> 1;             // row 0..511
    const int bx = C & 1;              // half-row 0..1

    const int t = threadIdx.x;
    const int w = bx * 256 + t;

    // ---- per-wave tap rotation (r12): decorrelate stall phases of co-resident
    //      waves. Taps commute (sum into acc); wave v starts at physical tap
    //      (2v + W) mod 9 and walks cyclically. readfirstlane pins the
    //      rotation to an SGPR so weight reads remain scalar s_loads.
    const int wave = __builtin_amdgcn_readfirstlane(t >> 6);
    int kcur = (wave * 2 + (W & 0xffff)) % KK;     // physical tap of prologue conv

    const size_t plane = (size_t)HH * WW;
    const float* xb = x + (size_t)b * CIN * plane;

    // ---- 3x3x3 zero-padded patch, flat index = c*9 + t; pad elem 27 = 0 ----
    float patch[28];
    patch[27] = 0.0f;
    #pragma unroll
    for (int c = 0; c < CIN; ++c) {
        const float* xp = xb + c * plane;
        #pragma unroll
        for (int tt = 0; tt < KK; ++tt) {
            const int yy = h + tt / 3 - 1;
            const int xx = w + tt % 3 - 1;
            const bool in = (yy >= 0) & (yy < HH) & (xx >= 0) & (xx < WW);
            patch[c * KK + tt] = in ? xp[yy * WW + xx] : 0.0f;
        }
    }

    const float hf = (float)h;
    const float wf = (float)w;

    float acc0 = b_def[0];
    float acc1 = b_def[1];
    float acc2 = b_def[2];

    // ---- prologue: conv for physical tap kcur, all-scalar (r9-proven) ----
    float oy, ox, om;
    {
        const float* blk = wsw + kcur * TAPBLK;
        float a0 = b_off[2 * kcur], a1 = b_off[2 * kcur + 1], s = b_off[18 + kcur];
        #pragma unroll
        for (int q = 0; q < 28; ++q) {
            a0 = fmaf(blk[2 * q],     patch[q], a0);
            a1 = fmaf(blk[2 * q + 1], patch[q], a1);
        }
        #pragma unroll
        for (int i = 0; i < 28; ++i) {
            s = fmaf(blk[56 + i], patch[i], s);
        }
        oy = a0; ox = a1; om = s;
    }

    // ---- software-pipelined tap loop (r9 schedule; physical taps rotate) ----
    // iter j: (A) issue gathers for tap kp  (B) conv next tap kn  (C) consume kp
    #pragma unroll 1
    for (int j = 1; j <= KK; ++j) {
        const int kp = kcur;                       // tap whose conv is in (oy,ox,om)
        const int kn = (kcur + 1 == KK) ? 0 : kcur + 1;
        const float* blkp = wsw + kp * TAPBLK;

        // -- phase A: contraction weights (uniform scalars) + sampling for tap kp --
        const float cw00 = blkp[84], cw01 = blkp[85], cw02 = blkp[86];
        const float cw10 = blkp[88], cw11 = blkp[89], cw12 = blkp[90];
        const float cw20 = blkp[92], cw21 = blkp[93], cw22 = blkp[94];

        const float m = 1.0f / (1.0f + __expf(-om));

        const float py = hf + (float)(kp / 3 - 1) + oy;
        const float px = wf + (float)(kp % 3 - 1) + ox;
        const float y0f = floorf(py);
        const float x0f = floorf(px);
        const float dy = py - y0f;
        const float dx = px - x0f;
        const int y0 = (int)y0f;
        const int x0 = (int)x0f;

        const float omdy = 1.0f - dy;
        const float omdx = 1.0f - dx;
        const float w00 = omdx * omdy;
        const float w01 = dx * omdy;
        const float w10 = omdx * dy;
        const float w11 = dx * dy;

        const int interior = (y0 >= 0) & (y0 + 1 < HH) & (x0 >= 0) & (x0 + 1 < WW);

        f2 vT0, vB0, vT1, vB1, vT2, vB2;   // gathered 2x2 corners per channel
        if (__all(interior)) {
            const int idx = y0 * WW + x0;
            const float* xp0 = xb + idx;
            const float* xp1 = xp0 + plane;
            const float* xp2 = xp1 + plane;
            vT0 = *(const f2u*)(xp0);  vB0 = *(const f2u*)(xp0 + WW);
            vT1 = *(const f2u*)(xp1);  vB1 = *(const f2u*)(xp1 + WW);
            vT2 = *(const f2u*)(xp2);  vB2 = *(const f2u*)(xp2 + WW);
        } else {
            const bool vy0 = (y0 >= 0)     & (y0 < HH);
            const bool vy1 = (y0 + 1 >= 0) & (y0 + 1 < HH);
            const bool vx0 = (x0 >= 0)     & (x0 < WW);
            const bool vx1 = (x0 + 1 >= 0) & (x0 + 1 < WW);

            const int yc0 = min(max(y0, 0), HH - 1);
            const int yc1 = min(max(y0 + 1, 0), HH - 1);
            const int xc0 = min(max(x0, 0), WW - 1);
            const int xc1 = min(max(x0 + 1, 0), WW - 1);

            const float* xp0 = xb;
            const float* xp1 = xp0 + plane;
            const float* xp2 = xp1 + plane;

            vT0.x = (vy0 & vx0) ? xp0[yc0 * WW + xc0] : 0.0f;
            vT0.y = (vy0 & vx1) ? xp0[yc0 * WW + xc1] : 0.0f;
            vB0.x = (vy1 & vx0) ? xp0[yc1 * WW + xc0] : 0.0f;
            vB0.y = (vy1 & vx1) ? xp0[yc1 * WW + xc1] : 0.0f;
            vT1.x = (vy0 & vx0) ? xp1[yc0 * WW + xc0] : 0.0f;
            vT1.y = (vy0 & vx1) ? xp1[yc0 * WW + xc1] : 0.0f;
            vB1.x = (vy1 & vx0) ? xp1[yc1 * WW + xc0] : 0.0f;
            vB1.y = (vy1 & vx1) ? xp1[yc1 * WW + xc1] : 0.0f;
            vT2.x = (vy0 & vx0) ? xp2[yc0 * WW + xc0] : 0.0f;
            vT2.y = (vy0 & vx1) ? xp2[yc0 * WW + xc1] : 0.0f;
            vB2.x = (vy1 & vx0) ? xp2[yc1 * WW + xc0] : 0.0f;
            vB2.y = (vy1 & vx1) ? xp2[yc1 * WW + xc1] : 0.0f;
        }

        // -- phase B: conv for next physical tap kn (independent of gathers) --
        if (j < KK) {
            const float* blk = wsw + kn * TAPBLK;
            float a0 = b_off[2 * kn], a1 = b_off[2 * kn + 1], s = b_off[18 + kn];
            #pragma unroll
            for (int q = 0; q < 28; ++q) {
                a0 = fmaf(blk[2 * q],     patch[q], a0);
                a1 = fmaf(blk[2 * q + 1], patch[q], a1);
            }
            #pragma unroll
            for (int i = 0; i < 28; ++i) {
                s = fmaf(blk[56 + i], patch[i], s);
            }
            oy = a0; ox = a1; om = s;
            kcur = kn;
        }

        // -- phase C: consume tap kp's gathers, all-scalar --
        {
            float v0 = vT0.x * w00;
            v0 = fmaf(vT0.y, w01, v0);
            v0 = fmaf(vB0.x, w10, v0);
            v0 = fmaf(vB0.y, w11, v0);
            const float val0 = v0 * m;

            float v1 = vT1.x * w00;
            v1 = fmaf(vT1.y, w01, v1);
            v1 = fmaf(vB1.x, w10, v1);
            v1 = fmaf(vB1.y, w11, v1);
            const float val1 = v1 * m;

            float v2 = vT2.x * w00;
            v2 = fmaf(vT2.y, w01, v2);
            v2 = fmaf(vB2.x, w10, v2);
            v2 = fmaf(vB2.y, w11, v2);
            const float val2 = v2 * m;

            acc0 = fmaf(cw00, val0, acc0);
            acc1 = fmaf(cw01, val0, acc1);
            acc2 = fmaf(cw02, val0, acc2);
            acc0 = fmaf(cw10, val1, acc0);
            acc1 = fmaf(cw11, val1, acc1);
            acc2 = fmaf(cw12, val1, acc2);
            acc0 = fmaf(cw20, val2, acc0);
            acc1 = fmaf(cw21, val2, acc1);
            acc2 = fmaf(cw22, val2, acc2);
        }
    }

    const size_t base = (size_t)b * (CIN * plane) + (size_t)h * WW + w;
    out[base]             = acc0;
    out[base + plane]     = acc1;
    out[base + 2 * plane] = acc2;
}

extern "C" void kernel_launch(void* const* d_in, const int* in_sizes, int n_in,
                              void* d_out, int out_size, void* d_ws, size_t ws_size,
                              hipStream_t stream) {
    const float* x     = (const float*)d_in[0];
    const float* w_off = (const float*)d_in[1];
    const float* b_off = (const float*)d_in[2];
    const float* w_def = (const float*)d_in[3];
    const float* b_def = (const float*)d_in[4];
    float* out = (float*)d_out;
    float* wsw = (float*)d_ws;   // 864 floats of reordered weights

    reorder_weights<<<1, 256, 0, stream>>>(w_off, w_def, wsw);

    dim3 block(256, 1, 1);
    dim3 grid(8192, 1, 1);   // flat; in-kernel XCD-aware swizzle decodes (b,h,bx)
    deform_fused_kernel<<<grid, block, 0, stream>>>(x, wsw, b_off, b_def, out);
}